// Round 11
// baseline (867.845 us; speedup 1.0000x reference)
//
#include <hip/hip_runtime.h>

#define P 16384
#define S 4096
#define NB 8
#define CAP 8

typedef unsigned long long u64;
typedef unsigned int u32;

// Opaque identity: forces separate rounding, blocks fma contraction across it.
#define OPAQUE(x) __asm__("" : "+v"(x))

// pd (f32, ref formula) -> u32 key monotone DESCENDING in pd; (dk<<32)|idx in
// ascending u64 order reproduces jax.lax.top_k (largest pd, ties->lower idx).
__device__ __forceinline__ u32 pd_to_dk(float pd) {
  pd = pd + 0.0f;                        // canonicalize -0 -> +0
  u32 b = __float_as_uint(pd);
  u32 s = (u32)((int)b >> 31);
  return b ^ (~(s | 0x80000000u));       // neg: b ; non-neg: b ^ 0x7FFFFFFF
}
__device__ __forceinline__ float dk_to_pd(u32 d) {
  u32 pb = (d & 0x80000000u) ? d : (d ^ 0x7FFFFFFFu);
  return __uint_as_float(pb);            // sentinel 0xFF800000 -> -inf
}
// 2-ulp step toward -inf; conservative lower bound for threshold transform.
__device__ __forceinline__ float prev2(float v) {
  u32 b = __float_as_uint(v);
  if ((b & 0x7F800000u) == 0x7F800000u) return v;   // +-inf: keep
  if (v > 0.0f) b -= 2;
  else if (v < 0.0f) b += 2;
  else return -1e-30f;
  return __uint_as_float(b);
}

__device__ __forceinline__ void insert16(u64 (&L)[16], u64 key) {
#pragma unroll
  for (int j = 15; j >= 1; --j) {
    u64 a = (L[j - 1] > key) ? L[j - 1] : key;
    L[j] = (L[j] > key) ? a : L[j];
  }
  L[0] = (L[0] > key) ? key : L[0];
}

// Exact key recompute from packed candidate (x0,x1,x2,xx) + query regs.
// Bit-identical to the scan/drain arithmetic.
__device__ __forceinline__ u64 key3(const float4* __restrict__ pk3b, u32 idx,
                                    float q0, float q1, float q2, float qq) {
  float4 v = pk3b[idx];
  float ip = __builtin_fmaf(v.z, q2, __builtin_fmaf(v.y, q1, v.x * q0));
  float a  = __builtin_fmaf(2.0f, ip, -v.w);
  float pd = a - qq;
  return ((u64)pd_to_dk(pd) << 32) | idx;
}

// ---------------- Kernel A: per-batch min/max of channels 0,1 ----------------
__global__ void kminmax(const float* __restrict__ x, float* __restrict__ mm) {
  int b = blockIdx.x;
  int tid = threadIdx.x;
  const float* x0 = x + (size_t)b * 5 * P;
  const float* x1 = x0 + P;
  float mn0 = __builtin_inff(), mx0 = -__builtin_inff();
  float mn1 = __builtin_inff(), mx1 = -__builtin_inff();
  for (int i = tid; i < P; i += 256) {
    float a = x0[i];
    mn0 = fminf(mn0, a); mx0 = fmaxf(mx0, a);
    float c = x1[i];
    mn1 = fminf(mn1, c); mx1 = fmaxf(mx1, c);
  }
  __shared__ float s0[256], s1[256], s2[256], s3[256];
  s0[tid] = mn0; s1[tid] = mx0; s2[tid] = mn1; s3[tid] = mx1;
  __syncthreads();
  for (int off = 128; off > 0; off >>= 1) {
    if (tid < off) {
      s0[tid] = fminf(s0[tid], s0[tid + off]);
      s1[tid] = fmaxf(s1[tid], s1[tid + off]);
      s2[tid] = fminf(s2[tid], s2[tid + off]);
      s3[tid] = fmaxf(s3[tid], s3[tid + off]);
    }
    __syncthreads();
  }
  if (tid == 0) {
    mm[b * 4 + 0] = s0[0];
    mm[b * 4 + 1] = s1[0];
    mm[b * 4 + 2] = s2[0];
    mm[b * 4 + 3] = s3[0];
  }
}

// ------------- Kernel P: pack candidates (exact ref roundings for xx) -------
// pk2[p] = (x0, x1, xx2d, 0) ; pk3[p] = (x0, x1, x2, xx3d)
__global__ void kprep(const float* __restrict__ x, float4* __restrict__ pk2,
                      float4* __restrict__ pk3) {
#pragma clang fp contract(off)
  int gid = blockIdx.x * 256 + threadIdx.x;   // 0 .. NB*P-1
  int b = gid >> 14;
  int i = gid & (P - 1);
  const float* xs = x + (size_t)b * 5 * P;
  float x0 = xs[i], x1 = xs[P + i], x2 = xs[2 * P + i];
  float t0 = x0 * x0; OPAQUE(t0);
  float t1 = x1 * x1; OPAQUE(t1);
  float t2 = x2 * x2; OPAQUE(t2);
  float s2 = t0 + t1;
  pk2[gid] = make_float4(x0, x1, s2, 0.0f);
  pk3[gid] = make_float4(x0, x1, x2, s2 + t2);
}

// ---------------- Kernel B: 1-NN in 2D, 8-way candidate split ---------------
// grid NB*64*8: (b, sgrp, eighth); 4 waves scan 512 cands each.
__global__ __launch_bounds__(256) void kidx1(const float4* __restrict__ pk2,
                                             const float* __restrict__ mm,
                                             u64* __restrict__ bests1) {
#pragma clang fp contract(off)
  int blk = blockIdx.x;
  int b = blk >> 9;
  int sgrp = (blk >> 3) & 63;
  int eighth = blk & 7;
  int w = threadIdx.x >> 6, l = threadIdx.x & 63;
  float mn0 = mm[b * 4 + 0], mx0 = mm[b * 4 + 1];
  float mn1 = mm[b * 4 + 2], mx1 = mm[b * 4 + 3];
  float m0 = (float)l * (1.0f / 64.0f);
  float m1 = (float)sgrp * (1.0f / 64.0f);
  float d0 = mx0 - mn0, d1 = mx1 - mn1;
  float p0 = m0 * d0; OPAQUE(p0);
  float q0 = p0 + mn0;
  float p1 = m1 * d1; OPAQUE(p1);
  float q1 = p1 + mn1;
  float sq0 = q0 * q0; OPAQUE(sq0);
  float sq1 = q1 * q1; OPAQUE(sq1);
  float qq = sq0 + sq1;

  int base = eighth * 2048 + w * 512;
  const float4* pc = pk2 + (size_t)b * P + base;
  float best_pd = -__builtin_inff();
  u32 best_idx = 0;
  for (int j = 0; j < 128; ++j) {
#pragma unroll
    for (int t = 0; t < 4; ++t) {
      float4 v = pc[(j << 2) + t];
      // ip = fma(x1,q1, round(x0*q0)); pd = fma(2,ip,-xx) - qq
      float ip = __builtin_fmaf(v.y, q1, v.x * q0);
      float a  = __builtin_fmaf(2.0f, ip, -v.z);
      float pd = a - qq;
      bool bt = pd > best_pd;   // strict: ties keep earlier (lower idx)
      best_pd  = bt ? pd : best_pd;
      best_idx = bt ? (u32)(base + (j << 2) + t) : best_idx;
    }
  }
  u64 key = ((u64)pd_to_dk(best_pd) << 32) | best_idx;
  __shared__ u64 kb[4][64];
  kb[w][l] = key;
  __syncthreads();
  if (threadIdx.x < 64) {
    u64 m = kb[0][l];
    u64 t1 = kb[1][l]; m = (t1 < m) ? t1 : m;
    u64 t2 = kb[2][l]; m = (t2 < m) ? t2 : m;
    u64 t3 = kb[3][l]; m = (t3 < m) ? t3 : m;
    bests1[((size_t)((b * 64 + sgrp) * 8 + eighth) << 6) + l] = m;
  }
}

// ---------------- Kernel Q: merge eighths, gather query xyz -----------------
__global__ void kq(const float* __restrict__ x, const u64* __restrict__ bests1,
                   float* __restrict__ qx, float* __restrict__ qy,
                   float* __restrict__ qz) {
  int qi = blockIdx.x * 256 + threadIdx.x;   // 0..NB*S-1
  int b = qi >> 12;
  int s = qi & 4095;
  int sgrp = s >> 6, l = s & 63;
  size_t o = ((size_t)((b * 64 + sgrp) * 8) << 6) + l;
  u64 m = bests1[o];
#pragma unroll
  for (int i = 1; i < 8; ++i) {
    u64 t = bests1[o + (size_t)i * 64];
    m = (t < m) ? t : m;
  }
  u32 idx = (u32)m;
  const float* xs = x + (size_t)b * 5 * P;
  qx[qi] = xs[idx];
  qy[qi] = xs[P + idx];
  qz[qi] = xs[2 * P + idx];
}

// ---------------- Kernel C: 16-NN scan over half range, 4 waves, CAP 8 ------
// grid NB*64*2: (b, sgrp, half). Per-wave top-16 -> in-block pair-merge ->
// 2 idx-lists per (query, half) streamed to global partial (4 lists/query).
__global__ __launch_bounds__(256, 6) void kidx2(const float4* __restrict__ pk3,
                                                const float* __restrict__ qx,
                                                const float* __restrict__ qy,
                                                const float* __restrict__ qz,
                                                u32* __restrict__ partial) {
#pragma clang fp contract(off)
  __shared__ u64 buf[256 * (CAP + 1)];   // 18.4 KB scan rows; aliased by stage
  u32* stage = (u32*)buf;                // [4][64][16] idx lists (16 KB)
  int blk = blockIdx.x;
  int b = blk >> 7;
  int rest = blk & 127;
  int sgrp = rest >> 1, half = rest & 1;
  int w = threadIdx.x >> 6, l = threadIdx.x & 63;
  int qi = (b << 12) + (sgrp << 6) + l;
  float q0 = qx[qi], q1 = qy[qi], q2 = qz[qi];
  float sq0 = q0 * q0; OPAQUE(sq0);
  float sq1 = q1 * q1; OPAQUE(sq1);
  float sq2 = q2 * q2; OPAQUE(sq2);
  float qq = (sq0 + sq1) + sq2;
  const float4* pk3b = pk3 + (size_t)b * P;
  int base = half * 8192 + w * 2048;
  const float4* pc = pk3b + base;

  u64 L[16];
#pragma unroll
  for (int k = 0; k < 16; ++k) L[k] = 0xFF800000FFFFFFFFull;  // dk(-inf)|idx
  float thrA = -__builtin_inff();
  int cnt = 0;
  u64* bufp = buf + threadIdx.x * (CAP + 1);

  auto drain = [&]() {
    while (__any(cnt > 0)) {
      if (cnt > 0) {
        --cnt;
        u64 e = bufp[cnt];
        float pd = __uint_as_float((u32)(e >> 32)) - qq;  // exact ref rounding
        u64 key = ((u64)pd_to_dk(pd) << 32) | (u32)e;
        if (key < L[15]) insert16(L, key);
      }
    }
    float tp = dk_to_pd((u32)(L[15] >> 32));
    thrA = prev2(tp + qq);     // -inf stays -inf
  };

  for (int j = 0; j < 512; ++j) {
#pragma unroll
    for (int t = 0; t < 4; ++t) {
      float4 v = pc[(j << 2) + t];
      float ip = __builtin_fmaf(v.z, q2, __builtin_fmaf(v.y, q1, v.x * q0));
      float a  = __builtin_fmaf(2.0f, ip, -v.w);
      if (a >= thrA) {   // >=: equal-pd ties must survive for idx tie-break
        bufp[cnt] = ((u64)__float_as_uint(a) << 32) | (u32)(base + (j << 2) + t);
        ++cnt;
      }
    }
    // CAP 8, trigger at 4: cnt <= 3+4 = 7 < CAP, never overflows.
    if (__any(cnt >= CAP - 4)) drain();
  }
  drain();

  __syncthreads();               // all rows dead before aliasing as stage
#pragma unroll
  for (int k = 0; k < 16; ++k) stage[(w << 10) + (l << 4) + k] = (u32)L[k];
  __syncthreads();

  if ((w & 1) == 0) {
    // lane merges sorted lists of waves (w, w+1) for query l, streams idx out
    const u32* sa = stage + (w << 10) + (l << 4);
    const u32* sb = stage + ((w + 1) << 10) + (l << 4);
    int pa = 0, pb = 0;
    u32 ia = sa[0]; u64 ka = key3(pk3b, ia, q0, q1, q2, qq);
    u32 ib = sb[0]; u64 kb2 = key3(pk3b, ib, q0, q1, q2, qq);
    u32* outp = partial + ((((size_t)qi * 2 + half) * 2 + (w >> 1)) << 4);
    for (int k = 0; k < 16; ++k) {
      bool ta = ka < kb2;        // keys unique (disjoint idx)
      outp[k] = ta ? ia : ib;
      if (ta) {
        ++pa;
        if (pa < 16) { ia = sa[pa]; ka = key3(pk3b, ia, q0, q1, q2, qq); }
        else ka = ~0ULL;
      } else {
        ++pb;
        if (pb < 16) { ib = sb[pb]; kb2 = key3(pk3b, ib, q0, q1, q2, qq); }
        else kb2 = ~0ULL;
      }
    }
  }
}

// ---------------- Kernel M: 4-way exact merge + gather + output write -------
__global__ __launch_bounds__(256) void km(const float* __restrict__ x,
                                          const float4* __restrict__ pk3,
                                          const float* __restrict__ qx,
                                          const float* __restrict__ qy,
                                          const float* __restrict__ qz,
                                          const u32* __restrict__ partial,
                                          float* __restrict__ out) {
#pragma clang fp contract(off)
  __shared__ u32 mg[256][16];    // 16 KB
  int tid = threadIdx.x;
  int qi0 = blockIdx.x * 256;
  {
    int qi = qi0 + tid;
    int b = qi >> 12;
    float q0 = qx[qi], q1 = qy[qi], q2 = qz[qi];
    float sq0 = q0 * q0; OPAQUE(sq0);
    float sq1 = q1 * q1; OPAQUE(sq1);
    float sq2 = q2 * q2; OPAQUE(sq2);
    float qq = (sq0 + sq1) + sq2;
    const float4* pk3b = pk3 + (size_t)b * P;
    const u32* lp = partial + ((size_t)qi << 6);   // 4 sorted lists x 16
    int p0 = 0, p1 = 0, p2 = 0, p3 = 0;
    u32 i0 = lp[0],  i1 = lp[16], i2 = lp[32], i3 = lp[48];
    u64 h0 = key3(pk3b, i0, q0, q1, q2, qq);
    u64 h1 = key3(pk3b, i1, q0, q1, q2, qq);
    u64 h2 = key3(pk3b, i2, q0, q1, q2, qq);
    u64 h3 = key3(pk3b, i3, q0, q1, q2, qq);
#define ADVK(n, off) { ++p##n; \
    if (p##n < 16) { i##n = lp[(off) + p##n]; \
      h##n = key3(pk3b, i##n, q0, q1, q2, qq); } else h##n = ~0ULL; }
    for (int k = 0; k < 16; ++k) {
      u64 m01 = (h0 < h1) ? h0 : h1;
      u64 m23 = (h2 < h3) ? h2 : h3;
      u64 m = (m01 < m23) ? m01 : m23;
      mg[tid][k] = (u32)((m == h0) ? i0 : (m == h1) ? i1 : (m == h2) ? i2 : i3);
      if      (m == h0) ADVK(0, 0)
      else if (m == h1) ADVK(1, 16)
      else if (m == h2) ADVK(2, 32)
      else              ADVK(3, 48)
    }
#undef ADVK
  }
  __syncthreads();

  // gather/write: 4 passes x (64 queries x 4 k-quads); float4 stores
#pragma unroll
  for (int pass = 0; pass < 4; ++pass) {
    int lq = pass * 64 + (tid >> 2);
    int g = tid & 3;
    int qi = qi0 + lq;
    int b = qi >> 12;
    int s = qi & 4095;
    u32 j0 = mg[lq][g * 4 + 0];
    u32 j1 = mg[lq][g * 4 + 1];
    u32 j2 = mg[lq][g * 4 + 2];
    u32 j3 = mg[lq][g * 4 + 3];
#pragma unroll
    for (int c = 0; c < 5; ++c) {
      const float* xc = x + (size_t)(b * 5 + c) * P;
      float4 v;
      v.x = xc[j0]; v.y = xc[j1]; v.z = xc[j2]; v.w = xc[j3];
      float* op = out + (((size_t)(b * 5 + c) * S + s) << 4) + (g << 2);
      *(float4*)op = v;
    }
  }
}

extern "C" void kernel_launch(void* const* d_in, const int* in_sizes, int n_in,
                              void* d_out, int out_size, void* d_ws, size_t ws_size,
                              hipStream_t stream) {
  const float* x = (const float*)d_in[0];
  float* out = (float*)d_out;
  char* ws = (char*)d_ws;
  size_t off = 0;
  float*  mm     = (float*)(ws + off);  off += 1024;
  float4* pk2    = (float4*)(ws + off); off += (size_t)NB * P * 16;   // 2 MB
  float4* pk3    = (float4*)(ws + off); off += (size_t)NB * P * 16;   // 2 MB
  u64*    bests1 = (u64*)(ws + off);    off += (size_t)NB * 64 * 8 * 64 * 8; // 2 MB
  float*  qx     = (float*)(ws + off);  off += (size_t)NB * S * 4;
  float*  qy     = (float*)(ws + off);  off += (size_t)NB * S * 4;
  float*  qz     = (float*)(ws + off);  off += (size_t)NB * S * 4;    // 384 KB
  u32*    partial= (u32*)(ws + off);    off += (size_t)NB * S * 4 * 16 * 4; // 8.4 MB

  kminmax<<<NB, 256, 0, stream>>>(x, mm);
  kprep<<<NB * P / 256, 256, 0, stream>>>(x, pk2, pk3);
  kidx1<<<NB * 64 * 8, 256, 0, stream>>>(pk2, mm, bests1);
  kq<<<NB * S / 256, 256, 0, stream>>>(x, bests1, qx, qy, qz);
  kidx2<<<NB * 64 * 2, 256, 0, stream>>>(pk3, qx, qy, qz, partial);
  km<<<NB * S / 256, 256, 0, stream>>>(x, pk3, qx, qy, qz, partial, out);
}

// Round 12
// 782.167 us; speedup vs baseline: 1.1095x; 1.1095x over previous
//
#include <hip/hip_runtime.h>

#define P 16384
#define S 4096
#define NB 8

typedef unsigned long long u64;
typedef unsigned int u32;

// Opaque identity: forces separate rounding, blocks fma contraction across it.
#define OPAQUE(x) __asm__("" : "+v"(x))

// pd (f32, ref formula) -> u32 key monotone DESCENDING in pd; (dk<<32)|idx in
// ascending u64 order reproduces jax.lax.top_k (largest pd, ties->lower idx).
__device__ __forceinline__ u32 pd_to_dk(float pd) {
  pd = pd + 0.0f;                        // canonicalize -0 -> +0
  u32 b = __float_as_uint(pd);
  u32 s = (u32)((int)b >> 31);
  return b ^ (~(s | 0x80000000u));       // neg: b ; non-neg: b ^ 0x7FFFFFFF
}
__device__ __forceinline__ float dk_to_pd(u32 d) {
  u32 pb = (d & 0x80000000u) ? d : (d ^ 0x7FFFFFFFu);
  return __uint_as_float(pb);            // sentinel 0xFF800000 -> -inf
}
// 2-ulp step toward -inf; conservative lower bound for threshold transform.
__device__ __forceinline__ float prev2(float v) {
  u32 b = __float_as_uint(v);
  if ((b & 0x7F800000u) == 0x7F800000u) return v;   // +-inf: keep
  if (v > 0.0f) b -= 2;
  else if (v < 0.0f) b += 2;
  else return -1e-30f;
  return __uint_as_float(b);
}

// u32 sorted-insert ladder (values only): ~3 VALU/slot.
__device__ __forceinline__ void insert16u32(u32 (&L)[16], u32 key) {
#pragma unroll
  for (int j = 15; j >= 1; --j) {
    u32 a = (L[j - 1] > key) ? L[j - 1] : key;   // v_max_u32
    L[j] = (L[j] > key) ? a : L[j];
  }
  L[0] = (L[0] > key) ? key : L[0];              // v_min_u32
}

// ---------------- Kernel A: per-batch min/max of channels 0,1 ----------------
__global__ void kminmax(const float* __restrict__ x, float* __restrict__ mm) {
  int b = blockIdx.x;
  int tid = threadIdx.x;
  const float* x0 = x + (size_t)b * 5 * P;
  const float* x1 = x0 + P;
  float mn0 = __builtin_inff(), mx0 = -__builtin_inff();
  float mn1 = __builtin_inff(), mx1 = -__builtin_inff();
  for (int i = tid; i < P; i += 256) {
    float a = x0[i];
    mn0 = fminf(mn0, a); mx0 = fmaxf(mx0, a);
    float c = x1[i];
    mn1 = fminf(mn1, c); mx1 = fmaxf(mx1, c);
  }
  __shared__ float s0[256], s1[256], s2[256], s3[256];
  s0[tid] = mn0; s1[tid] = mx0; s2[tid] = mn1; s3[tid] = mx1;
  __syncthreads();
  for (int off = 128; off > 0; off >>= 1) {
    if (tid < off) {
      s0[tid] = fminf(s0[tid], s0[tid + off]);
      s1[tid] = fmaxf(s1[tid], s1[tid + off]);
      s2[tid] = fminf(s2[tid], s2[tid + off]);
      s3[tid] = fmaxf(s3[tid], s3[tid + off]);
    }
    __syncthreads();
  }
  if (tid == 0) {
    mm[b * 4 + 0] = s0[0];
    mm[b * 4 + 1] = s1[0];
    mm[b * 4 + 2] = s2[0];
    mm[b * 4 + 3] = s3[0];
  }
}

// ---------------- Kernel P: precompute xx (2D and 3D), exact ref roundings --
__global__ void kprep(const float* __restrict__ x, float* __restrict__ xx2d,
                      float* __restrict__ xx3d) {
#pragma clang fp contract(off)
  int gid = blockIdx.x * 256 + threadIdx.x;   // 0 .. NB*P-1
  int b = gid >> 14;
  int i = gid & (P - 1);
  const float* xs = x + (size_t)b * 5 * P;
  float x0 = xs[i], x1 = xs[P + i], x2 = xs[2 * P + i];
  float t0 = x0 * x0; OPAQUE(t0);
  float t1 = x1 * x1; OPAQUE(t1);
  float t2 = x2 * x2; OPAQUE(t2);
  float s2 = t0 + t1;
  xx2d[gid] = s2;
  xx3d[gid] = s2 + t2;
}

// ---------------- Kernel B: 1-NN in 2D, 4-way candidate split (r7) ----------
__global__ __launch_bounds__(256) void kidx1(const float* __restrict__ x,
                                             const float* __restrict__ mm,
                                             const float* __restrict__ xx2d,
                                             u64* __restrict__ bests1) {
#pragma clang fp contract(off)
  int blk = blockIdx.x;
  int b = blk >> 8;
  int sgrp = (blk >> 2) & 63;
  int qtr = blk & 3;
  int w = threadIdx.x >> 6, l = threadIdx.x & 63;
  const float* xs = x + (size_t)b * 5 * P;
  const float* ys = xs + P;
  float mn0 = mm[b * 4 + 0], mx0 = mm[b * 4 + 1];
  float mn1 = mm[b * 4 + 2], mx1 = mm[b * 4 + 3];
  float m0 = (float)l * (1.0f / 64.0f);
  float m1 = (float)sgrp * (1.0f / 64.0f);
  float d0 = mx0 - mn0, d1 = mx1 - mn1;
  float p0 = m0 * d0; OPAQUE(p0);
  float q0 = p0 + mn0;
  float p1 = m1 * d1; OPAQUE(p1);
  float q1 = p1 + mn1;
  float sq0 = q0 * q0; OPAQUE(sq0);
  float sq1 = q1 * q1; OPAQUE(sq1);
  float qq = sq0 + sq1;

  int base = qtr * 4096 + w * 1024;
  const float4* xs4 = (const float4*)(xs + base);
  const float4* ys4 = (const float4*)(ys + base);
  const float4* ws4 = (const float4*)(xx2d + b * P + base);
  float best_pd = -__builtin_inff();
  u32 best_idx = 0;
  for (int j = 0; j < 256; ++j) {
    float4 cx = xs4[j];
    float4 cy = ys4[j];
    float4 cw = ws4[j];
    float cxa[4] = {cx.x, cx.y, cx.z, cx.w};
    float cya[4] = {cy.x, cy.y, cy.z, cy.w};
    float cwa[4] = {cw.x, cw.y, cw.z, cw.w};
#pragma unroll
    for (int t = 0; t < 4; ++t) {
      // ip = fma(x1,q1, round(x0*q0)); pd = fma(2,ip,-xx) - qq
      float ip = __builtin_fmaf(cya[t], q1, cxa[t] * q0);
      float a  = __builtin_fmaf(2.0f, ip, -cwa[t]);
      float pd = a - qq;
      bool bt = pd > best_pd;   // strict: ties keep earlier (lower idx)
      best_pd  = bt ? pd : best_pd;
      best_idx = bt ? (u32)(base + (j << 2) + t) : best_idx;
    }
  }
  u64 key = ((u64)pd_to_dk(best_pd) << 32) | best_idx;
  __shared__ u64 kb[4][64];
  kb[w][l] = key;
  __syncthreads();
  if (threadIdx.x < 64) {
    u64 m = kb[0][l];
    u64 t1 = kb[1][l]; m = (t1 < m) ? t1 : m;
    u64 t2 = kb[2][l]; m = (t2 < m) ? t2 : m;
    u64 t3 = kb[3][l]; m = (t3 < m) ? t3 : m;
    bests1[((size_t)((b * 64 + sgrp) * 4 + qtr) << 6) + l] = m;
  }
}

// ---------------- Kernel Q: merge quarters, gather query xyz (r7) -----------
__global__ void kq(const float* __restrict__ x, const u64* __restrict__ bests1,
                   float* __restrict__ qx, float* __restrict__ qy,
                   float* __restrict__ qz) {
  int qi = blockIdx.x * 256 + threadIdx.x;   // 0..NB*S-1
  int b = qi >> 12;
  int s = qi & 4095;
  int sgrp = s >> 6, l = s & 63;
  size_t o = ((size_t)((b * 64 + sgrp) * 4) << 6) + l;
  u64 m = bests1[o];
  u64 t;
  t = bests1[o + 64];  m = (t < m) ? t : m;
  t = bests1[o + 128]; m = (t < m) ? t : m;
  t = bests1[o + 192]; m = (t < m) ? t : m;
  u32 idx = (u32)m;
  const float* xs = x + (size_t)b * 5 * P;
  qx[qi] = xs[idx];
  qy[qi] = xs[P + idx];
  qz[qi] = xs[2 * P + idx];
}

// ---------------- Kernel C: 16-NN, value-pass (u32) + exact collect pass ----
// 512 threads, 8 waves x 2048-cand ranges (r7 geometry).
// Phase A: top-16 dk VALUES per (query,range) via u32 ladder; LDS buffers raw
//   a-bits. Gives T (16th value) and c< exactly.
// Phase B: streaming rescan; accept pd>T_pd plus first (16-c<) pd==T_pd in
//   index order -> exactly the range's top-16 with jax tie-break. Writes
//   (dk<<32|idx) u64 to a private 16-row; Batcher-sorts in registers.
// Then r7's verified 8-way merge + epilogue.
__global__ __launch_bounds__(512) void kidx2(const float* __restrict__ x,
                                             const float* __restrict__ xx3d,
                                             const float* __restrict__ qx,
                                             const float* __restrict__ qy,
                                             const float* __restrict__ qz,
                                             float* __restrict__ out) {
#pragma clang fp contract(off)
  __shared__ u64 smem[512 * 17];   // 69.6 KB: Phase-A u32 rows / key rows
  __shared__ u64 mgf[64][17];      // 9.2 KB merged lists
  const int tid = threadIdx.x;
  int b = blockIdx.x >> 6, sgrp = blockIdx.x & 63;
  int w = tid >> 6, l = tid & 63;
  int qi = (b << 12) + (sgrp << 6) + l;
  float q0 = qx[qi], q1 = qy[qi], q2 = qz[qi];
  float sq0 = q0 * q0; OPAQUE(sq0);
  float sq1 = q1 * q1; OPAQUE(sq1);
  float sq2 = q2 * q2; OPAQUE(sq2);
  float qq = (sq0 + sq1) + sq2;
  const float* xs = x + (size_t)b * 5 * P;
  const float* ys = xs + P;
  const float* zs = xs + 2 * P;
  int base = w * 2048;
  const float4* xs4 = (const float4*)(xs + base);
  const float4* ys4 = (const float4*)(ys + base);
  const float4* zs4 = (const float4*)(zs + base);
  const float4* ws4 = (const float4*)(xx3d + b * P + base);

  // ---- Phase A: 16 smallest dk values in range ----
  u32 L[16];
#pragma unroll
  for (int k = 0; k < 16; ++k) L[k] = 0xFF800000u;  // dk(pd=-inf) sentinel
  float thrA = -__builtin_inff();
  int cnt = 0;
  u32* arow = (u32*)smem + tid * 13;   // CAP 12 rows (stride 13 for banks)

  auto drainA = [&]() {
    while (__any(cnt > 0)) {
      if (cnt > 0) {
        --cnt;
        float av = __uint_as_float(arow[cnt]);
        float pd = av - qq;            // exact ref rounding
        u32 dk = pd_to_dk(pd);
        if (dk < L[15]) insert16u32(L, dk);
      }
    }
    float tp = dk_to_pd(L[15]);        // sentinel -> -inf
    thrA = prev2(tp + qq);             // -inf stays -inf
  };

  for (int j = 0; j < 512; ++j) {
    float4 cx = xs4[j];
    float4 cy = ys4[j];
    float4 cz = zs4[j];
    float4 cw = ws4[j];
    float cxa[4] = {cx.x, cx.y, cx.z, cx.w};
    float cya[4] = {cy.x, cy.y, cy.z, cy.w};
    float cza[4] = {cz.x, cz.y, cz.z, cz.w};
    float cwa[4] = {cw.x, cw.y, cw.z, cw.w};
#pragma unroll
    for (int t = 0; t < 4; ++t) {
      float ip = __builtin_fmaf(cza[t], q2,
                                __builtin_fmaf(cya[t], q1, cxa[t] * q0));
      float a  = __builtin_fmaf(2.0f, ip, -cwa[t]);
      if (a >= thrA) { arow[cnt] = __float_as_uint(a); ++cnt; }
    }
    // trigger 8: cnt <= 7+4 = 11 < 12, never overflows
    if (__any(cnt >= 8)) drainA();
  }
  drainA();

  u32 T = L[15];
  int c_lt = 0;
#pragma unroll
  for (int k = 0; k < 15; ++k) c_lt += (L[k] < T) ? 1 : 0;
  int need = 16 - c_lt;                // eq-ties wanted, in index order
  float T_pd = dk_to_pd(T);

  __syncthreads();   // Phase A buffers dead before key rows are written

  // ---- Phase B: exact-16 collect (streaming, no inserts) ----
  u64* srow = smem + (size_t)tid * 17;
  int pc2 = 0, eqc = 0;
  for (int j = 0; j < 512; ++j) {
    float4 cx = xs4[j];
    float4 cy = ys4[j];
    float4 cz = zs4[j];
    float4 cw = ws4[j];
    float cxa[4] = {cx.x, cx.y, cx.z, cx.w};
    float cya[4] = {cy.x, cy.y, cy.z, cy.w};
    float cza[4] = {cz.x, cz.y, cz.z, cz.w};
    float cwa[4] = {cw.x, cw.y, cw.z, cw.w};
#pragma unroll
    for (int t = 0; t < 4; ++t) {
      float ip = __builtin_fmaf(cza[t], q2,
                                __builtin_fmaf(cya[t], q1, cxa[t] * q0));
      float a  = __builtin_fmaf(2.0f, ip, -cwa[t]);
      float pd = a - qq;               // exact ref rounding
      bool lt = pd > T_pd;             // dk < T
      bool eq = (pd == T_pd) && (eqc < need);
      if ((lt || eq) && pc2 < 16) {
        u32 dk = pd_to_dk(pd);
        srow[pc2] = ((u64)dk << 32) | (u32)(base + (j << 2) + t);
        ++pc2;
        eqc += eq ? 1 : 0;
      }
    }
  }

  // ---- sort own 16 keys in registers (Batcher odd-even mergesort, static) --
  u64 K[16];
#pragma unroll
  for (int k = 0; k < 16; ++k) K[k] = srow[k];
#pragma unroll
  for (int p = 1; p < 16; p <<= 1) {
#pragma unroll
    for (int k = p; k >= 1; k >>= 1) {
#pragma unroll
      for (int j = k & (p - 1); j + k < 16; j += 2 * k) {
#pragma unroll
        for (int i = 0; i < k; ++i) {
          int aa = i + j, bb = i + j + k;
          if (bb < 16 && (aa / (2 * p)) == (bb / (2 * p))) {
            u64 xa = K[aa], xb = K[bb];
            bool g = xa > xb;
            K[aa] = g ? xb : xa;
            K[bb] = g ? xa : xb;
          }
        }
      }
    }
  }
#pragma unroll
  for (int k = 0; k < 16; ++k) srow[k] = K[k];
  __syncthreads();

  // ---- 8-way lazy merge (r7 verbatim, rows at (wv*64+l)*17) ----
  if (w == 0) {
    int p0 = 0, p1 = 0, p2 = 0, p3 = 0, p4 = 0, p5 = 0, p6 = 0, p7 = 0;
    u64 h0 = smem[(size_t)(0 * 64 + l) * 17], h1 = smem[(size_t)(1 * 64 + l) * 17];
    u64 h2 = smem[(size_t)(2 * 64 + l) * 17], h3 = smem[(size_t)(3 * 64 + l) * 17];
    u64 h4 = smem[(size_t)(4 * 64 + l) * 17], h5 = smem[(size_t)(5 * 64 + l) * 17];
    u64 h6 = smem[(size_t)(6 * 64 + l) * 17], h7 = smem[(size_t)(7 * 64 + l) * 17];
#define ADV(i) { ++p##i; h##i = (p##i < 16) ? smem[(size_t)(i * 64 + l) * 17 + p##i] : ~0ULL; }
    for (int k = 0; k < 16; ++k) {
      u64 m01 = (h0 < h1) ? h0 : h1;
      u64 m23 = (h2 < h3) ? h2 : h3;
      u64 m45 = (h4 < h5) ? h4 : h5;
      u64 m67 = (h6 < h7) ? h6 : h7;
      u64 ma = (m01 < m23) ? m01 : m23;
      u64 mb = (m45 < m67) ? m45 : m67;
      u64 m = (ma < mb) ? ma : mb;
      mgf[l][k] = m;
      if      (m == h0) ADV(0)
      else if (m == h1) ADV(1)
      else if (m == h2) ADV(2)
      else if (m == h3) ADV(3)
      else if (m == h4) ADV(4)
      else if (m == h5) ADV(5)
      else if (m == h6) ADV(6)
      else              ADV(7)
    }
#undef ADV
  }
  __syncthreads();

  // ---- epilogue: thread -> (query row, k-pair); coalesced float2 stores ----
  int qrow = tid >> 3;
  int g = tid & 7;
  int sOut = (sgrp << 6) + qrow;
  u32 i0 = (u32)mgf[qrow][g * 2 + 0];
  u32 i1 = (u32)mgf[qrow][g * 2 + 1];
#pragma unroll
  for (int c = 0; c < 5; ++c) {
    const float* xc = x + (size_t)(b * 5 + c) * P;
    float2 v;
    v.x = xc[i0]; v.y = xc[i1];
    float* op = out + (((size_t)(b * 5 + c) * S + sOut) << 4) + (g << 1);
    *(float2*)op = v;
  }
}

extern "C" void kernel_launch(void* const* d_in, const int* in_sizes, int n_in,
                              void* d_out, int out_size, void* d_ws, size_t ws_size,
                              hipStream_t stream) {
  const float* x = (const float*)d_in[0];
  float* out = (float*)d_out;
  char* ws = (char*)d_ws;
  float* mm    = (float*)ws;                         // 1 KB
  float* xx2d  = (float*)(ws + 1024);                // 512 KB
  float* xx3d  = (float*)(ws + 1024 + 524288);       // 512 KB
  u64*   bests1= (u64*)  (ws + 1024 + 2 * 524288);   // NB*64*4*64 u64 = 1 MB
  float* qx    = (float*)(ws + 1024 + 2 * 524288 + 1048576);  // 128 KB
  float* qy    = qx + NB * S;
  float* qz    = qy + NB * S;

  kminmax<<<NB, 256, 0, stream>>>(x, mm);
  kprep<<<NB * P / 256, 256, 0, stream>>>(x, xx2d, xx3d);
  kidx1<<<NB * 256, 256, 0, stream>>>(x, mm, xx2d, bests1);
  kq<<<NB * S / 256, 256, 0, stream>>>(x, bests1, qx, qy, qz);
  kidx2<<<NB * 64, 512, 0, stream>>>(x, xx3d, qx, qy, qz, out);
}

// Round 13
// 727.255 us; speedup vs baseline: 1.1933x; 1.0755x over previous
//
#include <hip/hip_runtime.h>

#define P 16384
#define S 4096
#define NB 8
#define CAP 16

typedef unsigned long long u64;
typedef unsigned int u32;

// Opaque identity: forces separate rounding, blocks fma contraction across it.
#define OPAQUE(x) __asm__("" : "+v"(x))

// pd (f32, ref formula) -> u32 key monotone DESCENDING in pd; (dk<<32)|idx in
// ascending u64 order reproduces jax.lax.top_k (largest pd, ties->lower idx).
__device__ __forceinline__ u32 pd_to_dk(float pd) {
  pd = pd + 0.0f;                        // canonicalize -0 -> +0
  u32 b = __float_as_uint(pd);
  u32 s = (u32)((int)b >> 31);
  return b ^ (~(s | 0x80000000u));       // neg: b ; non-neg: b ^ 0x7FFFFFFF
}
__device__ __forceinline__ float dk_to_pd(u32 d) {
  u32 pb = (d & 0x80000000u) ? d : (d ^ 0x7FFFFFFFu);
  return __uint_as_float(pb);            // sentinel 0xFF800000 -> -inf
}
// 2-ulp step toward -inf; conservative lower bound for threshold transform.
__device__ __forceinline__ float prev2(float v) {
  u32 b = __float_as_uint(v);
  if ((b & 0x7F800000u) == 0x7F800000u) return v;   // +-inf: keep
  if (v > 0.0f) b -= 2;
  else if (v < 0.0f) b += 2;
  else return -1e-30f;
  return __uint_as_float(b);
}

__device__ __forceinline__ void insert16(u64 (&L)[16], u64 key) {
#pragma unroll
  for (int j = 15; j >= 1; --j) {
    u64 a = (L[j - 1] > key) ? L[j - 1] : key;
    L[j] = (L[j] > key) ? a : L[j];
  }
  L[0] = (L[0] > key) ? key : L[0];
}

// ---------------- Kernel A: per-batch min/max of channels 0,1 ----------------
__global__ void kminmax(const float* __restrict__ x, float* __restrict__ mm) {
  int b = blockIdx.x;
  int tid = threadIdx.x;
  const float* x0 = x + (size_t)b * 5 * P;
  const float* x1 = x0 + P;
  float mn0 = __builtin_inff(), mx0 = -__builtin_inff();
  float mn1 = __builtin_inff(), mx1 = -__builtin_inff();
  for (int i = tid; i < P; i += 256) {
    float a = x0[i];
    mn0 = fminf(mn0, a); mx0 = fmaxf(mx0, a);
    float c = x1[i];
    mn1 = fminf(mn1, c); mx1 = fmaxf(mx1, c);
  }
  __shared__ float s0[256], s1[256], s2[256], s3[256];
  s0[tid] = mn0; s1[tid] = mx0; s2[tid] = mn1; s3[tid] = mx1;
  __syncthreads();
  for (int off = 128; off > 0; off >>= 1) {
    if (tid < off) {
      s0[tid] = fminf(s0[tid], s0[tid + off]);
      s1[tid] = fmaxf(s1[tid], s1[tid + off]);
      s2[tid] = fminf(s2[tid], s2[tid + off]);
      s3[tid] = fmaxf(s3[tid], s3[tid + off]);
    }
    __syncthreads();
  }
  if (tid == 0) {
    mm[b * 4 + 0] = s0[0];
    mm[b * 4 + 1] = s1[0];
    mm[b * 4 + 2] = s2[0];
    mm[b * 4 + 3] = s3[0];
  }
}

// ------------- Kernel P: pack candidates (exact ref roundings for xx) -------
// pk2[p] = (x0, x1, xx2d, 0) ; pk3[p] = (x0, x1, x2, xx3d)   [r10, verified]
__global__ void kprep(const float* __restrict__ x, float4* __restrict__ pk2,
                      float4* __restrict__ pk3) {
#pragma clang fp contract(off)
  int gid = blockIdx.x * 256 + threadIdx.x;   // 0 .. NB*P-1
  int b = gid >> 14;
  int i = gid & (P - 1);
  const float* xs = x + (size_t)b * 5 * P;
  float x0 = xs[i], x1 = xs[P + i], x2 = xs[2 * P + i];
  float t0 = x0 * x0; OPAQUE(t0);
  float t1 = x1 * x1; OPAQUE(t1);
  float t2 = x2 * x2; OPAQUE(t2);
  float s2 = t0 + t1;
  pk2[gid] = make_float4(x0, x1, s2, 0.0f);
  pk3[gid] = make_float4(x0, x1, x2, s2 + t2);
}

// ---------------- Kernel B: 1-NN in 2D, 4-way split + 4-deep prefetch -------
// grid NB*64*4: (b, sgrp, quarter); 4 waves scan 1024 cands each (r7 geom).
__global__ __launch_bounds__(256) void kidx1(const float4* __restrict__ pk2,
                                             const float* __restrict__ mm,
                                             u64* __restrict__ bests1) {
#pragma clang fp contract(off)
  int blk = blockIdx.x;
  int b = blk >> 8;
  int sgrp = (blk >> 2) & 63;
  int qtr = blk & 3;
  int w = threadIdx.x >> 6, l = threadIdx.x & 63;
  float mn0 = mm[b * 4 + 0], mx0 = mm[b * 4 + 1];
  float mn1 = mm[b * 4 + 2], mx1 = mm[b * 4 + 3];
  float m0 = (float)l * (1.0f / 64.0f);
  float m1 = (float)sgrp * (1.0f / 64.0f);
  float d0 = mx0 - mn0, d1 = mx1 - mn1;
  float p0 = m0 * d0; OPAQUE(p0);
  float q0 = p0 + mn0;
  float p1 = m1 * d1; OPAQUE(p1);
  float q1 = p1 + mn1;
  float sq0 = q0 * q0; OPAQUE(sq0);
  float sq1 = q1 * q1; OPAQUE(sq1);
  float qq = sq0 + sq1;

  int base = qtr * 4096 + w * 1024;
  const float4* pc = pk2 + (size_t)b * P + base;
  float best_pd = -__builtin_inff();
  u32 best_idx = 0;

  float4 B0[4], B1[4], B2[4], B3[4];
#define LD1(buf, jv) { const float4* _p = pc + ((jv) << 2); \
  buf[0] = _p[0]; buf[1] = _p[1]; buf[2] = _p[2]; buf[3] = _p[3]; }
#define EV1(buf, jv) { _Pragma("unroll") \
  for (int t = 0; t < 4; ++t) { float4 v = buf[t]; \
    float ip = __builtin_fmaf(v.y, q1, v.x * q0); \
    float a  = __builtin_fmaf(2.0f, ip, -v.z); \
    float pd = a - qq; \
    bool bt = pd > best_pd; \
    best_pd  = bt ? pd : best_pd; \
    best_idx = bt ? (u32)(base + ((jv) << 2) + t) : best_idx; } }

  LD1(B0, 0) LD1(B1, 1) LD1(B2, 2) LD1(B3, 3)
  for (int jj = 0; jj < 64; ++jj) {
    int j0 = jj << 2;
    int nb = (jj < 63) ? ((jj + 1) << 2) : j0;   // clamp tail prefetch
    EV1(B0, j0)     LD1(B0, nb)
    EV1(B1, j0 + 1) LD1(B1, nb + 1)
    EV1(B2, j0 + 2) LD1(B2, nb + 2)
    EV1(B3, j0 + 3) LD1(B3, nb + 3)
  }
#undef LD1
#undef EV1

  u64 key = ((u64)pd_to_dk(best_pd) << 32) | best_idx;
  __shared__ u64 kb[4][64];
  kb[w][l] = key;
  __syncthreads();
  if (threadIdx.x < 64) {
    u64 m = kb[0][l];
    u64 t1 = kb[1][l]; m = (t1 < m) ? t1 : m;
    u64 t2 = kb[2][l]; m = (t2 < m) ? t2 : m;
    u64 t3 = kb[3][l]; m = (t3 < m) ? t3 : m;
    bests1[((size_t)((b * 64 + sgrp) * 4 + qtr) << 6) + l] = m;
  }
}

// ---------------- Kernel Q: merge quarters, gather query xyz (r7) -----------
__global__ void kq(const float* __restrict__ x, const u64* __restrict__ bests1,
                   float* __restrict__ qx, float* __restrict__ qy,
                   float* __restrict__ qz) {
  int qi = blockIdx.x * 256 + threadIdx.x;   // 0..NB*S-1
  int b = qi >> 12;
  int s = qi & 4095;
  int sgrp = s >> 6, l = s & 63;
  size_t o = ((size_t)((b * 64 + sgrp) * 4) << 6) + l;
  u64 m = bests1[o];
  u64 t;
  t = bests1[o + 64];  m = (t < m) ? t : m;
  t = bests1[o + 128]; m = (t < m) ? t : m;
  t = bests1[o + 192]; m = (t < m) ? t : m;
  u32 idx = (u32)m;
  const float* xs = x + (size_t)b * 5 * P;
  qx[qi] = xs[idx];
  qy[qi] = xs[P + idx];
  qz[qi] = xs[2 * P + idx];
}

// ---------------- Kernel C: 16-NN, r7 machinery + packed/prefetched loads ---
// 512 threads, 8 waves x 2048-cand ranges; CAP16, trigger cnt>=12 (r7).
__global__ __launch_bounds__(512) void kidx2(const float4* __restrict__ pk3,
                                             const float* __restrict__ x,
                                             const float* __restrict__ qx,
                                             const float* __restrict__ qy,
                                             const float* __restrict__ qz,
                                             float* __restrict__ out) {
#pragma clang fp contract(off)
  __shared__ u64 buf[512][CAP + 1];   // 69.6 KB (r7)
  __shared__ u64 mgf[64][17];         // 8.7 KB merged lists (r7)
  int b = blockIdx.x >> 6, sgrp = blockIdx.x & 63;
  int w = threadIdx.x >> 6, l = threadIdx.x & 63;
  int qi = (b << 12) + (sgrp << 6) + l;
  float q0 = qx[qi], q1 = qy[qi], q2 = qz[qi];
  float sq0 = q0 * q0; OPAQUE(sq0);
  float sq1 = q1 * q1; OPAQUE(sq1);
  float sq2 = q2 * q2; OPAQUE(sq2);
  float qq = (sq0 + sq1) + sq2;
  int base = w * 2048;
  const float4* pc = pk3 + (size_t)b * P + base;

  u64 L[16];
#pragma unroll
  for (int k = 0; k < 16; ++k) L[k] = 0xFF800000FFFFFFFFull;  // dk(-inf)|idx
  float thrA = -__builtin_inff();
  int cnt = 0;
  u64* bufp = buf[threadIdx.x];

  auto drain = [&]() {
    while (__any(cnt > 0)) {
      if (cnt > 0) {
        --cnt;
        u64 e = bufp[cnt];
        float pd = __uint_as_float((u32)(e >> 32)) - qq;  // exact ref rounding
        u64 key = ((u64)pd_to_dk(pd) << 32) | (u32)e;
        if (key < L[15]) insert16(L, key);
      }
    }
    float tp = dk_to_pd((u32)(L[15] >> 32));
    thrA = prev2(tp + qq);     // -inf stays -inf
  };

  float4 A0[4], A1[4], A2[4], A3[4];
#define LD2(bufr, jv) { const float4* _p = pc + ((jv) << 2); \
  bufr[0] = _p[0]; bufr[1] = _p[1]; bufr[2] = _p[2]; bufr[3] = _p[3]; }
#define EV2(bufr, jv) { _Pragma("unroll") \
  for (int t = 0; t < 4; ++t) { float4 v = bufr[t]; \
    float ip = __builtin_fmaf(v.z, q2, __builtin_fmaf(v.y, q1, v.x * q0)); \
    float a  = __builtin_fmaf(2.0f, ip, -v.w); \
    if (a >= thrA) { \
      bufp[cnt] = ((u64)__float_as_uint(a) << 32) | (u32)(base + ((jv) << 2) + t); \
      ++cnt; \
    } } \
  if (__any(cnt >= CAP - 4)) drain(); }

  LD2(A0, 0) LD2(A1, 1) LD2(A2, 2) LD2(A3, 3)
  for (int jj = 0; jj < 128; ++jj) {
    int j0 = jj << 2;
    int nb = (jj < 127) ? ((jj + 1) << 2) : j0;   // clamp tail prefetch
    EV2(A0, j0)     LD2(A0, nb)
    EV2(A1, j0 + 1) LD2(A1, nb + 1)
    EV2(A2, j0 + 2) LD2(A2, nb + 2)
    EV2(A3, j0 + 3) LD2(A3, nb + 3)
  }
#undef LD2
#undef EV2
  drain();

  // lists -> buf rows (cnt==0 everywhere; rows are free, 16 <= CAP+1)  (r7)
#pragma unroll
  for (int k = 0; k < 16; ++k) bufp[k] = L[k];
  __syncthreads();

  if (w == 0) {
    // 8-way lazy merge for query l: lists live at rows {wv*64+l}  (r7)
    int p0 = 0, p1 = 0, p2 = 0, p3 = 0, p4 = 0, p5 = 0, p6 = 0, p7 = 0;
    u64 h0 = buf[l][0],        h1 = buf[64 + l][0];
    u64 h2 = buf[128 + l][0],  h3 = buf[192 + l][0];
    u64 h4 = buf[256 + l][0],  h5 = buf[320 + l][0];
    u64 h6 = buf[384 + l][0],  h7 = buf[448 + l][0];
#define ADV(i) { ++p##i; h##i = (p##i < 16) ? buf[i * 64 + l][p##i] : ~0ULL; }
    for (int k = 0; k < 16; ++k) {
      u64 m01 = (h0 < h1) ? h0 : h1;
      u64 m23 = (h2 < h3) ? h2 : h3;
      u64 m45 = (h4 < h5) ? h4 : h5;
      u64 m67 = (h6 < h7) ? h6 : h7;
      u64 ma = (m01 < m23) ? m01 : m23;
      u64 mb = (m45 < m67) ? m45 : m67;
      u64 m = (ma < mb) ? ma : mb;
      mgf[l][k] = m;
      if      (m == h0) ADV(0)
      else if (m == h1) ADV(1)
      else if (m == h2) ADV(2)
      else if (m == h3) ADV(3)
      else if (m == h4) ADV(4)
      else if (m == h5) ADV(5)
      else if (m == h6) ADV(6)
      else              ADV(7)
    }
#undef ADV
  }
  __syncthreads();

  // epilogue: thread -> (query row, k-pair); coalesced float2 stores (r7)
  int qrow = threadIdx.x >> 3;
  int g = threadIdx.x & 7;
  int sOut = (sgrp << 6) + qrow;
  u32 i0 = (u32)mgf[qrow][g * 2 + 0];
  u32 i1 = (u32)mgf[qrow][g * 2 + 1];
#pragma unroll
  for (int c = 0; c < 5; ++c) {
    const float* xc = x + (size_t)(b * 5 + c) * P;
    float2 v;
    v.x = xc[i0]; v.y = xc[i1];
    float* op = out + (((size_t)(b * 5 + c) * S + sOut) << 4) + (g << 1);
    *(float2*)op = v;
  }
}

extern "C" void kernel_launch(void* const* d_in, const int* in_sizes, int n_in,
                              void* d_out, int out_size, void* d_ws, size_t ws_size,
                              hipStream_t stream) {
  const float* x = (const float*)d_in[0];
  float* out = (float*)d_out;
  char* ws = (char*)d_ws;
  size_t off = 0;
  float*  mm     = (float*)(ws + off);  off += 1024;
  float4* pk2    = (float4*)(ws + off); off += (size_t)NB * P * 16;        // 2 MB
  float4* pk3    = (float4*)(ws + off); off += (size_t)NB * P * 16;        // 2 MB
  u64*    bests1 = (u64*)(ws + off);    off += (size_t)NB * 64 * 4 * 64 * 8; // 1 MB
  float*  qx     = (float*)(ws + off);  off += (size_t)NB * S * 4;
  float*  qy     = (float*)(ws + off);  off += (size_t)NB * S * 4;
  float*  qz     = (float*)(ws + off);  off += (size_t)NB * S * 4;         // 384 KB

  kminmax<<<NB, 256, 0, stream>>>(x, mm);
  kprep<<<NB * P / 256, 256, 0, stream>>>(x, pk2, pk3);
  kidx1<<<NB * 256, 256, 0, stream>>>(pk2, mm, bests1);
  kq<<<NB * S / 256, 256, 0, stream>>>(x, bests1, qx, qy, qz);
  kidx2<<<NB * 64, 512, 0, stream>>>(pk3, x, qx, qy, qz, out);
}